// Round 3
// baseline (239.873 us; speedup 1.0000x reference)
//
#include <hip/hip_runtime.h>
#include <hip/hip_bf16.h>

// Problem constants (from reference)
#define HD 64
#define VOCAB 64
#define SEQ 48
#define MEMSLOTS 4
#define TSTRIDE 68   // table row stride in floats: 64 data + 4 pad.
                     // Multiple of 4 -> every 16B chunk (k0 multiple of 8) stays
                     // 16B-aligned for ds_read_b128; 68 mod 32 = 4 banks/row shift
                     // spreads gather bank-starts across 8 positions per quad.

using frag_ab = __attribute__((ext_vector_type(8))) short;   // 8 bf16 (4 VGPRs)
using frag_cd = __attribute__((ext_vector_type(4))) float;   // 4 fp32
typedef __attribute__((ext_vector_type(4))) float floatx4;

static __device__ inline unsigned short f2bf(float f) {
  // round-to-nearest-even fp32 -> bf16 (setup path only)
  unsigned u = __float_as_uint(f);
  unsigned r = (u + 0x7fffu + ((u >> 16) & 1u)) >> 16;
  return (unsigned short)r;
}

static __device__ inline unsigned pack_bf16(float lo, float hi) {
  float2 f2 = make_float2(lo, hi);
  __hip_bfloat162 h2 = __float22bfloat162_rn(f2);   // RNE; packed HW cvt where available
  unsigned u;
  __builtin_memcpy(&u, &h2, 4);
  return u;   // low 16 = lo, high 16 = hi
}

// Kernel A: build fused first-layer tables in workspace.
// T1[v][j] = sum_k embed[v][k]*W1[j][k] + b1[j]          (query half)
// T2[v][j] = 0.25 * sum_k embed[v][k]*W1[j][64+k]        (memory half, mean folded)
__global__ void build_tables(const float* __restrict__ embed,
                             const float* __restrict__ W1,
                             const float* __restrict__ b1,
                             float* __restrict__ T) {
  int v = blockIdx.x;    // 0..63
  int j = threadIdx.x;   // 0..63
  const float* e = embed + v * HD;
  const float* w1r = W1 + j * (2 * HD);
  float s1 = 0.f, s2 = 0.f;
  for (int k = 0; k < HD; ++k) {
    float ev = e[k];              // uniform per block -> scalar loads
    s1 += ev * w1r[k];
    s2 += ev * w1r[HD + k];
  }
  T[v * TSTRIDE + j] = s1 + b1[j];
  T[VOCAB * TSTRIDE + v * TSTRIDE + j] = 0.25f * s2;
}

// Kernel B: per 16-row batch per wave:
//  gather+sum 5 table rows from LDS (ds_read_b128, floatx4 pk-adds)
//  relu -> packed bf16 cvt -> 2 x mfma_f32_16x16x32_bf16 per n-tile
//  A operand = W2 fragments (held in regs), B operand = h fragments
//  -> D row index = output feature (quad*4+p contiguous) -> float4 stores
__global__ __launch_bounds__(256, 4) void lru_main(
    const int* __restrict__ seqs, const int* __restrict__ qtok,
    const float* __restrict__ W2, const float* __restrict__ b2,
    const float* __restrict__ T, float* __restrict__ out, int nbatch) {
  __shared__ float sT[2 * VOCAB * TSTRIDE];   // 34816 B: T1 then T2

  // cooperative stage of both tables (contiguous in ws)
  {
    const floatx4* src = (const floatx4*)T;
    floatx4* dst = (floatx4*)sT;
    const int n4 = 2 * VOCAB * TSTRIDE / 4;   // 2176
    for (int i = threadIdx.x; i < n4; i += blockDim.x) dst[i] = src[i];
  }
  __syncthreads();

  const int lane = threadIdx.x & 63;
  const int quad = lane >> 4;
  const int m    = lane & 15;
  const int k0   = quad * 8;

  // W2 fragments as MFMA *A* operand: A[i=lane&15][k=quad*8+j], i -> W2 row t*16+i.
  frag_ab af[4][2];
  for (int t = 0; t < 4; ++t)
    for (int s = 0; s < 2; ++s) {
      const float* w2r = W2 + (t * 16 + m) * HD + s * 32 + k0;
      for (int j = 0; j < 8; ++j) af[t][s][j] = (short)f2bf(w2r[j]);
    }
  // bias as float4 per tile: features t*16 + quad*4 .. +3
  floatx4 b2q[4];
  for (int t = 0; t < 4; ++t)
    b2q[t] = *(const floatx4*)(b2 + t * 16 + quad * 4);

  const int wave = blockIdx.x * (blockDim.x >> 6) + (threadIdx.x >> 6);
  const int nw   = gridDim.x * (blockDim.x >> 6);

  const float* T1 = sT;
  const float* T2 = sT + VOCAB * TSTRIDE;

  for (int b = wave; b < nbatch; b += nw) {
    const int rb  = b * 16;
    const int row = rb + m;                  // 4 quads redundantly load row m's tokens (L1-hit)
    const int q   = qtok[row];
    const int* sp = seqs + row * SEQ;
    const int ta  = sp[43];                  // col 43
    const int4 tb = *(const int4*)(sp + 44); // cols 44,45,46,(47 unused); 16B-aligned

    // gather + sum 5 table rows at my 16 k-slots: k = k0..k0+7 and 32+k0..32+k0+7
    // each row: 4 x ds_read_b128; accumulate as floatx4 (-> v_pk_add_f32)
    floatx4 v0, v1, v2, v3;
    {
      const floatx4* p1 = (const floatx4*)(T1 + q * TSTRIDE + k0);
      v0 = p1[0]; v1 = p1[1]; v2 = p1[8]; v3 = p1[9];   // +32 floats = +8 floatx4
      const int toks[4] = {ta, tb.x, tb.y, tb.z};
#pragma unroll
      for (int u = 0; u < 4; ++u) {
        const floatx4* p2 = (const floatx4*)(T2 + toks[u] * TSTRIDE + k0);
        v0 += p2[0]; v1 += p2[1]; v2 += p2[8]; v3 += p2[9];
      }
    }

    // relu (-> v_pk_max_f32)
#pragma unroll
    for (int c = 0; c < 4; ++c) {
      v0[c] = fmaxf(v0[c], 0.f);
      v1[c] = fmaxf(v1[c], 0.f);
      v2[c] = fmaxf(v2[c], 0.f);
      v3[c] = fmaxf(v3[c], 0.f);
    }

    // packed bf16 convert into h fragments (MFMA B operand: B[n=lane&15][k=quad*8+j])
    union { frag_ab v; unsigned u[4]; } A0, A1;
    A0.u[0] = pack_bf16(v0[0], v0[1]);
    A0.u[1] = pack_bf16(v0[2], v0[3]);
    A0.u[2] = pack_bf16(v1[0], v1[1]);
    A0.u[3] = pack_bf16(v1[2], v1[3]);
    A1.u[0] = pack_bf16(v2[0], v2[1]);
    A1.u[1] = pack_bf16(v2[2], v2[3]);
    A1.u[2] = pack_bf16(v3[0], v3[1]);
    A1.u[3] = pack_bf16(v3[2], v3[3]);

    // D = W2 . h^T : D[i][n] = out[rb+n][t*16+i]; C layout row=quad*4+p, col=lane&15
    frag_cd acc[4];
#pragma unroll
    for (int t = 0; t < 4; ++t) {
      acc[t] = (frag_cd){0.f, 0.f, 0.f, 0.f};
      acc[t] = __builtin_amdgcn_mfma_f32_16x16x32_bf16(af[t][0], A0.v, acc[t], 0, 0, 0);
      acc[t] = __builtin_amdgcn_mfma_f32_16x16x32_bf16(af[t][1], A1.v, acc[t], 0, 0, 0);
    }

    // store: lane holds out[rb+m][t*16+quad*4 .. +3] -> float4 stores
    float* orow = out + (size_t)(rb + m) * HD;
#pragma unroll
    for (int t = 0; t < 4; ++t) {
      floatx4 o = acc[t] + b2q[t];
      *(floatx4*)(orow + t * 16 + quad * 4) = o;
    }
  }
}

extern "C" void kernel_launch(void* const* d_in, const int* in_sizes, int n_in,
                              void* d_out, int out_size, void* d_ws, size_t ws_size,
                              hipStream_t stream) {
  const int*   seqs  = (const int*)d_in[0];
  const int*   qtok  = (const int*)d_in[1];
  const float* embed = (const float*)d_in[2];
  const float* W1    = (const float*)d_in[3];
  const float* b1    = (const float*)d_in[4];
  const float* W2    = (const float*)d_in[5];
  const float* b2    = (const float*)d_in[6];
  float* out = (float*)d_out;
  float* T   = (float*)d_ws;   // 2*64*68 floats = 34816 B

  const int B = in_sizes[1];        // number of rows (524288)
  const int nbatch = B / 16;

  build_tables<<<VOCAB, HD, 0, stream>>>(embed, W1, b1, T);
  lru_main<<<2048, 256, 0, stream>>>(seqs, qtok, W2, b2, T, out, nbatch);
}